// Round 20
// baseline (124.585 us; speedup 1.0000x reference)
//
#include <hip/hip_runtime.h>
#include <math.h>

#define BB 8
#define NN 2048
#define NPOINT 102
#define H_REP 0.0005f

typedef float v2f __attribute__((ext_vector_type(2)));

__device__ const int    c_ns[5] = {8, 12, 16, 20, 24};
__device__ const double c_p[5]  = {0.004, 0.006, 0.008, 0.01, 0.012};

// part layout (doubles): cdpart[512] | reppart[256] | ukpart[160]
#define OFF_CD 0
#define OFF_REP 512
#define OFF_UK 768
#define N_DBL 928

__device__ inline double aload_d(const double* p) {
    return __hip_atomic_load(p, __ATOMIC_RELAXED, __HIP_MEMORY_SCOPE_AGENT);
}

// branchless sorted-5 insert (keeps t0<=t1<=t2<=t3<=t4)
__device__ inline void ins5(float c, float& t0, float& t1, float& t2, float& t3, float& t4) {
    float lo;
    lo = fminf(t0, c); c = fmaxf(t0, c); t0 = lo;
    lo = fminf(t1, c); c = fmaxf(t1, c); t1 = lo;
    lo = fminf(t2, c); c = fmaxf(t2, c); t2 = lo;
    lo = fminf(t3, c); c = fmaxf(t3, c); t3 = lo;
    t4 = fminf(t4, c);
}

union SMemP1 {
    struct { float4 sB[NN]; float pm[4][128]; } cd;        // 34 KB
    struct { float4 sP[NN]; float pm[4][64][5]; } rep;     // 37.9 KB
    struct { float4 sP[NN]; float2 sl[2][4]; int sFi[NPOINT]; } fps;  // 32.5 KB
};

// ---------------- phase1 (r19 validated, 77.2 us) ----------------
// blocks [0,8)=fps  [8,264)=cd  [264,520)=rep
__global__ __launch_bounds__(256, 2) void k_phase1(const float* __restrict__ pred,
                                                   const float* __restrict__ gt,
                                                   int* __restrict__ fidx,
                                                   double* __restrict__ part,
                                                   int* __restrict__ done) {
    __shared__ SMemP1 sm;
    int bid = blockIdx.x;
    int tid = threadIdx.x;
    int lane = tid & 63, wid = tid >> 6;

    if (bid == 8 && tid == 0) *done = 0;  // zero tail completion counter (no memset)

    if (bid < 8) {
        // ========== FPS: 4 waves x 8 pts/lane, DPP argmax, 1-barrier slot merge,
        //   + speculative 4-candidate coord prefetch (r19, validated) ==========
        __builtin_amdgcn_s_setprio(1);
        int b = bid;
        const float* pp = pred + (size_t)b * NN * 3;
        float px[8], py[8], pz[8], dist[8];
#pragma unroll
        for (int k = 0; k < 8; k++) {
            int i = (wid << 9) + (k << 6) + lane;  // wave wid owns [wid*512, wid*512+512)
            float x = pp[i * 3 + 0], y = pp[i * 3 + 1], z = pp[i * 3 + 2];
            px[k] = x; py[k] = y; pz[k] = z; dist[k] = 1e10f;
            sm.fps.sP[i] = make_float4(x, y, z, 0.0f);
        }
        if (tid == 0) sm.fps.sFi[0] = 0;
        __syncthreads();
        float4 lp = sm.fps.sP[0];  // loop-carried winner coords (in registers)
#pragma unroll 1
        for (int step = 1; step < NPOINT; ++step) {
            float bv = -1.0f;
            int bi = 0;
#pragma unroll
            for (int k = 0; k < 8; k++) {
                float dx = px[k] - lp.x, dy = py[k] - lp.y, dz = pz[k] - lp.z;
                float nd = fminf(dist[k], dx * dx + dy * dy + dz * dz);
                dist[k] = nd;
                bool better = nd > bv;  // ascending k -> first-max kept (min global idx)
                bv = better ? nd : bv;
                bi = better ? ((wid << 9) + (k << 6) + lane) : bi;
            }
            // wave-64 argmax: row_ror 1,2,4,8 + bcast15/31 (idempotent -> bcast-safe)
            {
                float v2; int i2; bool take;
#define DPPC(CTRL)                                                                          \
                v2 = __int_as_float(__builtin_amdgcn_update_dpp(                            \
                        __float_as_int(bv), __float_as_int(bv), CTRL, 0xF, 0xF, false));    \
                i2 = __builtin_amdgcn_update_dpp(bi, bi, CTRL, 0xF, 0xF, false);            \
                take = (v2 > bv) || (v2 == bv && i2 < bi);                                  \
                bv = take ? v2 : bv; bi = take ? i2 : bi;
                DPPC(0x121)  // row_ror:1
                DPPC(0x122)  // row_ror:2
                DPPC(0x124)  // row_ror:4
                DPPC(0x128)  // row_ror:8
                DPPC(0x142)  // row_bcast15
                DPPC(0x143)  // row_bcast31
#undef DPPC
            }
            int pb = step & 1;
            if (lane == 63) sm.fps.sl[pb][wid] = make_float2(bv, __int_as_float(bi));
            __syncthreads();  // no pending vmem in loop -> lgkm-only drain
            // read the 4 wave-winner slots, immediately issue speculative coord reads;
            // the (value,idx) merge overlaps those reads.
            float2 s0 = sm.fps.sl[pb][0];
            float2 s1 = sm.fps.sl[pb][1];
            float2 s2 = sm.fps.sl[pb][2];
            float2 s3 = sm.fps.sl[pb][3];
            int i0 = __float_as_int(s0.y), i1 = __float_as_int(s1.y);
            int i2w = __float_as_int(s2.y), i3 = __float_as_int(s3.y);
            float4 c0 = sm.fps.sP[i0];  // 4 independent broadcast ds_read_b128
            float4 c1 = sm.fps.sP[i1];
            float4 c2 = sm.fps.sP[i2w];
            float4 c3 = sm.fps.sP[i3];
            // merge (ascending wave -> disjoint ascending idx ranges): track winner wave
            float fv = s0.x;
            int fi = i0, wsel = 0;
            bool t1 = (s1.x > fv) || (s1.x == fv && i1 < fi);
            fv = t1 ? s1.x : fv; fi = t1 ? i1 : fi; wsel = t1 ? 1 : wsel;
            bool t2 = (s2.x > fv) || (s2.x == fv && i2w < fi);
            fv = t2 ? s2.x : fv; fi = t2 ? i2w : fi; wsel = t2 ? 2 : wsel;
            bool t3 = (s3.x > fv) || (s3.x == fv && i3 < fi);
            fv = t3 ? s3.x : fv; fi = t3 ? i3 : fi; wsel = t3 ? 3 : wsel;
            // select winner coords from the 4 prefetched candidates
            float4 lo01 = (wsel & 1) ? c1 : c0;
            float4 hi23 = (wsel & 1) ? c3 : c2;
            lp = (wsel & 2) ? hi23 : lo01;
            if (tid == 0) sm.fps.sFi[step] = fi;
        }
        __syncthreads();
        for (int s = tid; s < NPOINT; s += 256) fidx[b * NPOINT + s] = sm.fps.sFi[s];
    } else if (bid < 264) {
        // ========== chamfer: 2 rows/lane (128 rows/block), 4 waves x 512-pt chunks ==========
        int r = bid - 8;
        int z = r >> 7;
        int b = (r >> 4) & 7;
        int xb = r & 15;
        const float* A = z ? pred : gt;
        const float* Bp = z ? gt : pred;
        const float* bb = Bp + (size_t)b * NN * 3;
        for (int j = tid; j < NN; j += 256) {
            sm.cd.sB[j] = make_float4(bb[j * 3 + 0], bb[j * 3 + 1], bb[j * 3 + 2], 0.0f);
        }
        int rowA = xb * 128 + lane;
        int rowB = rowA + 64;
        const float* aA = A + ((size_t)b * NN + rowA) * 3;
        const float* aB = A + ((size_t)b * NN + rowB) * 3;
        float axA = aA[0], ayA = aA[1], azA = aA[2];
        float axB = aB[0], ayB = aB[1], azB = aB[2];
        __syncthreads();
        float mnA = 1e30f, mnB = 1e30f;
        int j0 = wid * 512;
#pragma unroll 8
        for (int jj = 0; jj < 512; jj++) {
            float4 p = sm.cd.sB[j0 + jj];
            float dxA = axA - p.x, dyA = ayA - p.y, dzA = azA - p.z;
            mnA = fminf(mnA, dxA * dxA + dyA * dyA + dzA * dzA);
            float dxB = axB - p.x, dyB = ayB - p.y, dzB = azB - p.z;
            mnB = fminf(mnB, dxB * dxB + dyB * dyB + dzB * dzB);
        }
        sm.cd.pm[wid][lane] = mnA;
        sm.cd.pm[wid][64 + lane] = mnB;
        __syncthreads();
        if (tid < 128) {
            double v = (double)fminf(fminf(sm.cd.pm[0][tid], sm.cd.pm[1][tid]),
                                     fminf(sm.cd.pm[2][tid], sm.cd.pm[3][tid]));
            for (int off = 32; off; off >>= 1) v += __shfl_down(v, off, 64);
            if (lane == 0) part[OFF_CD + r * 2 + (tid >> 6)] = v;  // two slots/block
        }
    } else {
        // ========== repulsion: 4 waves x 512-pt chunks, 64 rows/block ==========
        int r = bid - 264;
        int b = r >> 5;
        int xb = r & 31;
        const float* pp = pred + (size_t)b * NN * 3;
        for (int j = tid; j < NN; j += 256) {
            sm.rep.sP[j] = make_float4(pp[j * 3 + 0], pp[j * 3 + 1], pp[j * 3 + 2], 0.0f);
        }
        int row = xb * 64 + lane;
        __syncthreads();
        float4 q = sm.rep.sP[row];
        float t0 = 1e30f, t1 = 1e30f, t2 = 1e30f, t3 = 1e30f, t4 = 1e30f;
        int j0 = wid * 512;
#pragma unroll 8
        for (int jj = 0; jj < 512; jj++) {
            float4 p = sm.rep.sP[j0 + jj];
            float dx = q.x - p.x, dy = q.y - p.y, dz = q.z - p.z;
            ins5(dx * dx + dy * dy + dz * dz, t0, t1, t2, t3, t4);
        }
        sm.rep.pm[wid][lane][0] = t0; sm.rep.pm[wid][lane][1] = t1;
        sm.rep.pm[wid][lane][2] = t2; sm.rep.pm[wid][lane][3] = t3;
        sm.rep.pm[wid][lane][4] = t4;
        __syncthreads();
        if (tid < 64) {
            t0 = sm.rep.pm[0][lane][0]; t1 = sm.rep.pm[0][lane][1]; t2 = sm.rep.pm[0][lane][2];
            t3 = sm.rep.pm[0][lane][3]; t4 = sm.rep.pm[0][lane][4];
#pragma unroll
            for (int w = 1; w < 4; w++) {
#pragma unroll
                for (int k = 0; k < 5; k++) ins5(sm.rep.pm[w][lane][k], t0, t1, t2, t3, t4);
            }
            float s = fmaxf(H_REP - t1, 0.f) + fmaxf(H_REP - t2, 0.f) +
                      fmaxf(H_REP - t3, 0.f) + fmaxf(H_REP - t4, 0.f);
            double v = (double)s;
            for (int off = 32; off; off >>= 1) v += __shfl_down(v, off, 64);
            if (tid == 0) part[OFF_REP + r] = v;
        }
    }
}

// ---------------- tail: 1 block/(pi,b); 256-query tiles + two-pass ball ----------------
// Compression exactness: pads duplicate the first-selected point; multiplicity cap 2
// preserves (min1,min2); query first-row weight = 1+ns-cnt. (absmax=0, r15-r19.)
union UTail {
    struct { float sx[NN], sy[NN], sz[NN]; } st;        // 24.6 KB (ball + cand staging)
    struct { float pm1[16][256], pm2[16][256]; } pm;    // 32 KB  (query merge, 256 slots)
};

__global__ __launch_bounds__(1024, 1) void k_tail(const float* __restrict__ pred,
                                                  const int* __restrict__ fidx,
                                                  double* __restrict__ part,
                                                  int* __restrict__ done,
                                                  const float* __restrict__ radius,
                                                  float* __restrict__ out) {
    __shared__ UTail ut;
    __shared__ unsigned short gidxL[2448];        // 4.9 KB (selected idx, stride ns)
    __shared__ v2f cX[1232], cY[1232], cZ[1232];  // 29.6 KB compressed candidates (<=2464)
    __shared__ int scnt[NPOINT];
    __shared__ int spre[NPOINT + 1];              // packed prefix: low16=queries, high16=cands
    __shared__ int lastFlag;
    int grp = blockIdx.x;                         // pi*8 + b
    int pi = grp >> 3, b = grp & 7;
    int ns = c_ns[pi];
    int tid = threadIdx.x, lane = tid & 63, wid = tid >> 6;
    const float* pp = pred + (size_t)b * NN * 3;
    double rd = sqrt(c_p[pi]);
    float r2 = (float)(rd * rd);

    // ---- stage cloud into LDS ----
    for (int t = tid; t < 3 * NN; t += 1024) {
        float v = pp[t];
        int idx = t / 3;
        int comp = t - idx * 3;
        if (comp == 0) ut.st.sx[idx] = v;
        else if (comp == 1) ut.st.sy[idx] = v;
        else ut.st.sz[idx] = v;
    }
    __syncthreads();

    // ---- ball: 102 centers over 16 waves; TWO-PASS per 256-chunk: 4 independent
    //      ballot masks (pipelined LDS+VALU), then cheap serial apply ----
    for (int c = wid; c < NPOINT; c += 16) {
        int ci = fidx[b * NPOINT + c];
        float cx = ut.st.sx[ci], cy = ut.st.sy[ci], cz = ut.st.sz[ci];
        float sc = cx * cx + cy * cy + cz * cz;
        int cnt = 0;
#pragma unroll 1
        for (int j0 = 0; j0 < NN; j0 += 256) {
            unsigned long long mk[4];
#pragma unroll
            for (int u = 0; u < 4; u++) {  // independent: no serial cnt dependency
                int j = j0 + (u << 6) + lane;
                float x = ut.st.sx[j], y = ut.st.sy[j], z = ut.st.sz[j];
                float sj = x * x + y * y + z * z;
                float d2 = fmaxf(sc + sj - 2.0f * (cx * x + cy * y + cz * z), 0.0f);
                mk[u] = __ballot(d2 < r2);
            }
#pragma unroll
            for (int u = 0; u < 4; u++) {  // serial but scalar-cheap
                bool prd = (mk[u] >> lane) & 1ull;
                if (prd) {
                    int pos = cnt + (int)__popcll(mk[u] & ((1ull << lane) - 1ull));
                    if (pos < ns) gidxL[c * ns + pos] = (unsigned short)(j0 + (u << 6) + lane);
                }
                cnt += (int)__popcll(mk[u]);
            }
        }
        if (lane == 0) scnt[c] = min(cnt, ns);  // cnt>=1 (center is in the cloud)
    }
    __syncthreads();
    // ---- packed exclusive prefix scan over 102 entries: wave 0 only ----
    if (wid == 0) {
        int e0 = (2 * lane < NPOINT) ? scnt[2 * lane] : 0;
        int e1 = (2 * lane + 1 < NPOINT) ? scnt[2 * lane + 1] : 0;
        int p0 = e0 | ((e0 + (e0 < ns ? 1 : 0)) << 16);
        int p1 = e1 | ((e1 + (e1 < ns ? 1 : 0)) << 16);
        int local = p0 + p1;
        int incl = local;
        for (int d = 1; d < 64; d <<= 1) {
            int t = __shfl_up(incl, d, 64);
            if (lane >= d) incl += t;
        }
        int excl = incl - local;
        if (2 * lane <= NPOINT) spre[2 * lane] = excl;
        if (2 * lane + 1 <= NPOINT) spre[2 * lane + 1] = excl + p0;
    }
    __syncthreads();
    int Q = spre[NPOINT] & 0xffff;
    int CC = spre[NPOINT] >> 16;
    int CCpad = (CC + 31) & ~31;                  // <= 2464
    // ---- stage compressed candidates (reads ut.st -> writes cX/cY/cZ) ----
    float* fX = (float*)cX; float* fY = (float*)cY; float* fZ = (float*)cZ;
    for (int s = tid; s < CCpad; s += 1024) {
        float x = 1e30f, y = 1e30f, z = 1e30f;
        if (s < CC) {
            int lo = 0, hi = NPOINT - 1;
#pragma unroll
            for (int it = 0; it < 7; ++it) {
                int mid = (lo + hi + 1) >> 1;
                bool ge = ((spre[mid] >> 16) <= s);
                lo = ge ? mid : lo;
                hi = ge ? hi : mid - 1;
            }
            int p = s - (spre[lo] >> 16);
            int dup = (scnt[lo] < ns) ? 1 : 0;
            int id = gidxL[lo * ns + max(0, p - dup)];
            x = ut.st.sx[id]; y = ut.st.sy[id]; z = ut.st.sz[id];
        }
        fX[s] = x; fY[s] = y; fZ[s] = z;
    }
    __syncthreads();  // ut.st dead from here; ut.pm live (union)
    // ---- weighted compacted queries: 256-query tiles (4/lane) — one tile typical ----
    int CHp = CCpad >> 5;                          // v2f pairs per wave
    int j0p = wid * CHp;
    double racc = 0.0;
    for (int tb = 0; tb < Q; tb += 256) {
        float qx[4], qy[4], qz[4];
        double wgt[4];
#pragma unroll
        for (int hh = 0; hh < 4; hh++) {
            int q = tb + lane + 64 * hh;
            qx[hh] = 0.f; qy[hh] = 0.f; qz[hh] = 0.f; wgt[hh] = 0.0;
            if (q < Q) {
                int lo = 0, hi = NPOINT - 1;
#pragma unroll
                for (int it = 0; it < 7; ++it) {
                    int mid = (lo + hi + 1) >> 1;
                    bool ge = ((spre[mid] & 0xffff) <= q);
                    lo = ge ? mid : lo;
                    hi = ge ? hi : mid - 1;
                }
                int p = q - (spre[lo] & 0xffff);
                int dup = (scnt[lo] < ns) ? 1 : 0;
                int cslot = (spre[lo] >> 16) + (p == 0 ? 0 : p + dup);
                qx[hh] = fX[cslot]; qy[hh] = fY[cslot]; qz[hh] = fZ[cslot];
                wgt[hh] = (p == 0) ? (double)(1 + ns - scnt[lo]) : 1.0;
            }
        }
        v2f m1[4], m2[4];
#pragma unroll
        for (int hh = 0; hh < 4; hh++) { m1[hh] = (v2f){1e30f, 1e30f}; m2[hh] = (v2f){1e30f, 1e30f}; }
#pragma unroll 2
        for (int jj = 0; jj < CHp; jj++) {
            v2f X = cX[j0p + jj], Y = cY[j0p + jj], Z = cZ[j0p + jj];
            // direct formula: exact 0 for bit-identical duplicates
#pragma unroll
            for (int hh = 0; hh < 4; hh++) {
                v2f qvx = {qx[hh], qx[hh]}, qvy = {qy[hh], qy[hh]}, qvz = {qz[hh], qz[hh]};
                v2f dx = qvx - X, dy = qvy - Y, dz = qvz - Z;
                v2f d = dx * dx + dy * dy + dz * dz;
                float l0 = fminf(m1[hh].x, d.x), h0 = fmaxf(m1[hh].x, d.x);
                float l1 = fminf(m1[hh].y, d.y), h1 = fmaxf(m1[hh].y, d.y);
                m1[hh] = (v2f){l0, l1};
                m2[hh] = (v2f){fminf(m2[hh].x, h0), fminf(m2[hh].y, h1)};
            }
        }
        // merge even/odd streams (multiset (min1,min2) is order-independent -> exact)
#pragma unroll
        for (int hh = 0; hh < 4; hh++) {
            float a1 = fminf(m1[hh].x, m1[hh].y);
            float a2 = fminf(fmaxf(m1[hh].x, m1[hh].y), fminf(m2[hh].x, m2[hh].y));
            ut.pm.pm1[wid][64 * hh + lane] = a1;
            ut.pm.pm2[wid][64 * hh + lane] = a2;
        }
        __syncthreads();
        if (tid < 256) {
            float c1 = ut.pm.pm1[0][tid], c2 = ut.pm.pm2[0][tid];
#pragma unroll
            for (int w = 1; w < 16; w++) {
                float d1 = ut.pm.pm1[w][tid], d2 = ut.pm.pm2[w][tid];
                float n1 = fminf(c1, d1);
                float n2 = fminf(fmaxf(c1, d1), fminf(c2, d2));
                c1 = n1; c2 = n2;
            }
            int q = tb + tid;
            double v = 0.0;
            if (q < Q) v = wgt[tid >> 6] * (double)(sqrtf(c2) + 1e-8f);
            for (int off = 32; off; off >>= 1) v += __shfl_down(v, off, 64);
            if ((tid & 63) == 0) racc += v;
        }
        __syncthreads();  // pm reuse next tile
    }
    if (tid < 256 && (tid & 63) == 0) part[OFF_UK + grp * 4 + (tid >> 6)] = racc;
    // -------- last-block-done: fused finalize --------
    __threadfence();
    __syncthreads();
    if (tid == 0) lastFlag = (atomicAdd(done, 1) == 39);
    __syncthreads();
    if (!lastFlag) return;
    __threadfence();
    if (tid >= 64) return;
    double s0 = 0.0, s1 = 0.0, sr = 0.0;
#pragma unroll
    for (int k = 0; k < 4; k++) {
        s0 += aload_d(&part[OFF_CD + lane + 64 * k]);
        s1 += aload_d(&part[OFF_CD + 256 + lane + 64 * k]);
        sr += aload_d(&part[OFF_REP + lane + 64 * k]);
    }
    double v = 0.0;
    if (lane < 40) {
        int pi2 = lane >> 3;
        double m = 0.0;
#pragma unroll
        for (int k = 0; k < 4; k++) m += aload_d(&part[OFF_UK + lane * 4 + k]);
        double p = c_p[pi2];
        int M2 = NPOINT * c_ns[pi2];
        double disk_area = M_PI * 1.0 / (double)NN;
        double e = sqrt(disk_area);
        m = m / (double)M2;
        double d = m - e;
        double w = (p * 100.0) * (p * 100.0);
        v = d * d / (e + 1e-8) * w / 40.0;  // /(8 batches * 5 percentages)
    }
    for (int off = 32; off; off >>= 1) {
        v += __shfl_down(v, off, 64);
        s0 += __shfl_down(s0, off, 64);
        s1 += __shfl_down(s1, off, 64);
        sr += __shfl_down(sr, off, 64);
    }
    if (lane == 0) {
        double cd = (0.8 * s0 + 0.2 * s1) / ((double)BB * NN) / (double)radius[0];
        double rep = sr / ((double)BB * NN * 4.0);
        out[0] = (float)(cd + rep + v);
    }
}

extern "C" void kernel_launch(void* const* d_in, const int* in_sizes, int n_in,
                              void* d_out, int out_size, void* d_ws, size_t ws_size,
                              hipStream_t stream) {
    const float* pred = (const float*)d_in[0];
    const float* gt = (const float*)d_in[1];
    const float* radius = (const float*)d_in[2];
    float* out = (float*)d_out;

    double* part = (double*)d_ws;            // 928 doubles of per-block partials
    int* ints = (int*)(part + N_DBL);
    int* done = ints;                        // zeroed by phase1 block 8
    int* fidx = ints + 16;                   // 8*102

    hipLaunchKernelGGL(k_phase1, dim3(520), dim3(256), 0, stream, pred, gt, fidx, part, done);
    hipLaunchKernelGGL(k_tail, dim3(40), dim3(1024), 0, stream, pred, fidx, part, done,
                       radius, out);
}

// Round 21
// 117.536 us; speedup vs baseline: 1.0600x; 1.0600x over previous
//
#include <hip/hip_runtime.h>
#include <math.h>

#define BB 8
#define NN 2048
#define NPOINT 102
#define H_REP 0.0005f

typedef float v2f __attribute__((ext_vector_type(2)));

__device__ const int    c_ns[5] = {8, 12, 16, 20, 24};
__device__ const double c_p[5]  = {0.004, 0.006, 0.008, 0.01, 0.012};

// part layout (doubles): cdpart[512] | reppart[256] | ukpart[80]
#define OFF_CD 0
#define OFF_REP 512
#define OFF_UK 768
#define N_DBL 896

__device__ inline double aload_d(const double* p) {
    return __hip_atomic_load(p, __ATOMIC_RELAXED, __HIP_MEMORY_SCOPE_AGENT);
}

// branchless sorted-5 insert (keeps t0<=t1<=t2<=t3<=t4)
__device__ inline void ins5(float c, float& t0, float& t1, float& t2, float& t3, float& t4) {
    float lo;
    lo = fminf(t0, c); c = fmaxf(t0, c); t0 = lo;
    lo = fminf(t1, c); c = fmaxf(t1, c); t1 = lo;
    lo = fminf(t2, c); c = fmaxf(t2, c); t2 = lo;
    lo = fminf(t3, c); c = fmaxf(t3, c); t3 = lo;
    t4 = fminf(t4, c);
}

union SMemP1 {
    struct { float4 sB[NN]; float pm[4][128]; } cd;        // 34 KB
    struct { float4 sP[NN]; float pm[4][64][5]; } rep;     // 37.9 KB
    struct { float4 sP[NN]; float2 sl[2][4]; int sFi[NPOINT]; } fps;  // 32.5 KB
};

// ---------------- phase1 (r19 validated, 77.2 us) ----------------
// blocks [0,8)=fps  [8,264)=cd  [264,520)=rep
__global__ __launch_bounds__(256, 2) void k_phase1(const float* __restrict__ pred,
                                                   const float* __restrict__ gt,
                                                   int* __restrict__ fidx,
                                                   double* __restrict__ part,
                                                   int* __restrict__ done) {
    __shared__ SMemP1 sm;
    int bid = blockIdx.x;
    int tid = threadIdx.x;
    int lane = tid & 63, wid = tid >> 6;

    if (bid == 8 && tid == 0) *done = 0;  // zero tail completion counter (no memset)

    if (bid < 8) {
        // ========== FPS: 4 waves x 8 pts/lane, DPP argmax, 1-barrier slot merge,
        //   + speculative 4-candidate coord prefetch (r19, validated) ==========
        __builtin_amdgcn_s_setprio(1);
        int b = bid;
        const float* pp = pred + (size_t)b * NN * 3;
        float px[8], py[8], pz[8], dist[8];
#pragma unroll
        for (int k = 0; k < 8; k++) {
            int i = (wid << 9) + (k << 6) + lane;  // wave wid owns [wid*512, wid*512+512)
            float x = pp[i * 3 + 0], y = pp[i * 3 + 1], z = pp[i * 3 + 2];
            px[k] = x; py[k] = y; pz[k] = z; dist[k] = 1e10f;
            sm.fps.sP[i] = make_float4(x, y, z, 0.0f);
        }
        if (tid == 0) sm.fps.sFi[0] = 0;
        __syncthreads();
        float4 lp = sm.fps.sP[0];  // loop-carried winner coords (in registers)
#pragma unroll 1
        for (int step = 1; step < NPOINT; ++step) {
            float bv = -1.0f;
            int bi = 0;
#pragma unroll
            for (int k = 0; k < 8; k++) {
                float dx = px[k] - lp.x, dy = py[k] - lp.y, dz = pz[k] - lp.z;
                float nd = fminf(dist[k], dx * dx + dy * dy + dz * dz);
                dist[k] = nd;
                bool better = nd > bv;  // ascending k -> first-max kept (min global idx)
                bv = better ? nd : bv;
                bi = better ? ((wid << 9) + (k << 6) + lane) : bi;
            }
            // wave-64 argmax: row_ror 1,2,4,8 + bcast15/31 (idempotent -> bcast-safe)
            {
                float v2; int i2; bool take;
#define DPPC(CTRL)                                                                          \
                v2 = __int_as_float(__builtin_amdgcn_update_dpp(                            \
                        __float_as_int(bv), __float_as_int(bv), CTRL, 0xF, 0xF, false));    \
                i2 = __builtin_amdgcn_update_dpp(bi, bi, CTRL, 0xF, 0xF, false);            \
                take = (v2 > bv) || (v2 == bv && i2 < bi);                                  \
                bv = take ? v2 : bv; bi = take ? i2 : bi;
                DPPC(0x121)  // row_ror:1
                DPPC(0x122)  // row_ror:2
                DPPC(0x124)  // row_ror:4
                DPPC(0x128)  // row_ror:8
                DPPC(0x142)  // row_bcast15
                DPPC(0x143)  // row_bcast31
#undef DPPC
            }
            int pb = step & 1;
            if (lane == 63) sm.fps.sl[pb][wid] = make_float2(bv, __int_as_float(bi));
            __syncthreads();  // no pending vmem in loop -> lgkm-only drain
            // read the 4 wave-winner slots, then IMMEDIATELY issue speculative coord
            // reads for all 4 candidates; the (value,idx) merge overlaps those reads.
            float2 s0 = sm.fps.sl[pb][0];
            float2 s1 = sm.fps.sl[pb][1];
            float2 s2 = sm.fps.sl[pb][2];
            float2 s3 = sm.fps.sl[pb][3];
            int i0 = __float_as_int(s0.y), i1 = __float_as_int(s1.y);
            int i2w = __float_as_int(s2.y), i3 = __float_as_int(s3.y);
            float4 c0 = sm.fps.sP[i0];  // 4 independent broadcast ds_read_b128
            float4 c1 = sm.fps.sP[i1];
            float4 c2 = sm.fps.sP[i2w];
            float4 c3 = sm.fps.sP[i3];
            // merge (ascending wave -> disjoint ascending idx ranges): track winner wave
            float fv = s0.x;
            int fi = i0, wsel = 0;
            bool t1 = (s1.x > fv) || (s1.x == fv && i1 < fi);
            fv = t1 ? s1.x : fv; fi = t1 ? i1 : fi; wsel = t1 ? 1 : wsel;
            bool t2 = (s2.x > fv) || (s2.x == fv && i2w < fi);
            fv = t2 ? s2.x : fv; fi = t2 ? i2w : fi; wsel = t2 ? 2 : wsel;
            bool t3 = (s3.x > fv) || (s3.x == fv && i3 < fi);
            fv = t3 ? s3.x : fv; fi = t3 ? i3 : fi; wsel = t3 ? 3 : wsel;
            // select winner coords from the 4 prefetched candidates
            float4 lo01 = (wsel & 1) ? c1 : c0;
            float4 hi23 = (wsel & 1) ? c3 : c2;
            lp = (wsel & 2) ? hi23 : lo01;
            if (tid == 0) sm.fps.sFi[step] = fi;
        }
        __syncthreads();
        for (int s = tid; s < NPOINT; s += 256) fidx[b * NPOINT + s] = sm.fps.sFi[s];
    } else if (bid < 264) {
        // ========== chamfer: 2 rows/lane (128 rows/block), 4 waves x 512-pt chunks ==========
        int r = bid - 8;
        int z = r >> 7;
        int b = (r >> 4) & 7;
        int xb = r & 15;
        const float* A = z ? pred : gt;
        const float* Bp = z ? gt : pred;
        const float* bb = Bp + (size_t)b * NN * 3;
        for (int j = tid; j < NN; j += 256) {
            sm.cd.sB[j] = make_float4(bb[j * 3 + 0], bb[j * 3 + 1], bb[j * 3 + 2], 0.0f);
        }
        int rowA = xb * 128 + lane;
        int rowB = rowA + 64;
        const float* aA = A + ((size_t)b * NN + rowA) * 3;
        const float* aB = A + ((size_t)b * NN + rowB) * 3;
        float axA = aA[0], ayA = aA[1], azA = aA[2];
        float axB = aB[0], ayB = aB[1], azB = aB[2];
        __syncthreads();
        float mnA = 1e30f, mnB = 1e30f;
        int j0 = wid * 512;
#pragma unroll 8
        for (int jj = 0; jj < 512; jj++) {
            float4 p = sm.cd.sB[j0 + jj];
            float dxA = axA - p.x, dyA = ayA - p.y, dzA = azA - p.z;
            mnA = fminf(mnA, dxA * dxA + dyA * dyA + dzA * dzA);
            float dxB = axB - p.x, dyB = ayB - p.y, dzB = azB - p.z;
            mnB = fminf(mnB, dxB * dxB + dyB * dyB + dzB * dzB);
        }
        sm.cd.pm[wid][lane] = mnA;
        sm.cd.pm[wid][64 + lane] = mnB;
        __syncthreads();
        if (tid < 128) {
            double v = (double)fminf(fminf(sm.cd.pm[0][tid], sm.cd.pm[1][tid]),
                                     fminf(sm.cd.pm[2][tid], sm.cd.pm[3][tid]));
            for (int off = 32; off; off >>= 1) v += __shfl_down(v, off, 64);
            if (lane == 0) part[OFF_CD + r * 2 + (tid >> 6)] = v;  // two slots/block
        }
    } else {
        // ========== repulsion: 4 waves x 512-pt chunks, 64 rows/block ==========
        int r = bid - 264;
        int b = r >> 5;
        int xb = r & 31;
        const float* pp = pred + (size_t)b * NN * 3;
        for (int j = tid; j < NN; j += 256) {
            sm.rep.sP[j] = make_float4(pp[j * 3 + 0], pp[j * 3 + 1], pp[j * 3 + 2], 0.0f);
        }
        int row = xb * 64 + lane;
        __syncthreads();
        float4 q = sm.rep.sP[row];
        float t0 = 1e30f, t1 = 1e30f, t2 = 1e30f, t3 = 1e30f, t4 = 1e30f;
        int j0 = wid * 512;
#pragma unroll 8
        for (int jj = 0; jj < 512; jj++) {
            float4 p = sm.rep.sP[j0 + jj];
            float dx = q.x - p.x, dy = q.y - p.y, dz = q.z - p.z;
            ins5(dx * dx + dy * dy + dz * dz, t0, t1, t2, t3, t4);
        }
        sm.rep.pm[wid][lane][0] = t0; sm.rep.pm[wid][lane][1] = t1;
        sm.rep.pm[wid][lane][2] = t2; sm.rep.pm[wid][lane][3] = t3;
        sm.rep.pm[wid][lane][4] = t4;
        __syncthreads();
        if (tid < 64) {
            t0 = sm.rep.pm[0][lane][0]; t1 = sm.rep.pm[0][lane][1]; t2 = sm.rep.pm[0][lane][2];
            t3 = sm.rep.pm[0][lane][3]; t4 = sm.rep.pm[0][lane][4];
#pragma unroll
            for (int w = 1; w < 4; w++) {
#pragma unroll
                for (int k = 0; k < 5; k++) ins5(sm.rep.pm[w][lane][k], t0, t1, t2, t3, t4);
            }
            float s = fmaxf(H_REP - t1, 0.f) + fmaxf(H_REP - t2, 0.f) +
                      fmaxf(H_REP - t3, 0.f) + fmaxf(H_REP - t4, 0.f);
            double v = (double)s;
            for (int off = 32; off; off >>= 1) v += __shfl_down(v, off, 64);
            if (tid == 0) part[OFF_REP + r] = v;
        }
    }
}

// ---------------- tail (r19 validated): 1 block/(pi,b) ----------------
// LDS-staged ball -> single-wave scan -> compressed kNN-2 -> last-block finalize.
// Compression exactness: pads duplicate the first-selected point; multiplicity cap 2
// preserves (min1,min2); query first-row weight = 1+ns-cnt. (absmax=0, r15-r19.)
union UTail {
    struct { float sx[NN], sy[NN], sz[NN]; } st;        // 24.6 KB (ball + cand staging)
    struct { float pm1[16][128], pm2[16][128]; } pm;    // 16 KB  (query merge)
};

__global__ __launch_bounds__(1024, 1) void k_tail(const float* __restrict__ pred,
                                                  const int* __restrict__ fidx,
                                                  double* __restrict__ part,
                                                  int* __restrict__ done,
                                                  const float* __restrict__ radius,
                                                  float* __restrict__ out) {
    __shared__ UTail ut;
    __shared__ unsigned short gidxL[2448];        // 4.9 KB (selected idx, stride ns)
    __shared__ v2f cX[1232], cY[1232], cZ[1232];  // 29.6 KB compressed candidates (<=2464)
    __shared__ int scnt[NPOINT];
    __shared__ int spre[NPOINT + 1];              // packed prefix: low16=queries, high16=cands
    __shared__ int lastFlag;
    int grp = blockIdx.x;                         // pi*8 + b
    int pi = grp >> 3, b = grp & 7;
    int ns = c_ns[pi];
    int tid = threadIdx.x, lane = tid & 63, wid = tid >> 6;
    const float* pp = pred + (size_t)b * NN * 3;
    double rd = sqrt(c_p[pi]);
    float r2 = (float)(rd * rd);

    // ---- stage cloud into LDS ----
    for (int t = tid; t < 3 * NN; t += 1024) {
        float v = pp[t];
        int idx = t / 3;
        int comp = t - idx * 3;
        if (comp == 0) ut.st.sx[idx] = v;
        else if (comp == 1) ut.st.sy[idx] = v;
        else ut.st.sz[idx] = v;
    }
    __syncthreads();

    // ---- ball: 102 center-tasks over 16 waves; full LDS scan (writes capped at ns) ----
    for (int c = wid; c < NPOINT; c += 16) {
        int ci = fidx[b * NPOINT + c];
        float cx = ut.st.sx[ci], cy = ut.st.sy[ci], cz = ut.st.sz[ci];
        float sc = cx * cx + cy * cy + cz * cz;
        int cnt = 0;
#pragma unroll 4
        for (int j0 = 0; j0 < NN; j0 += 64) {
            int j = j0 + lane;
            float x = ut.st.sx[j], y = ut.st.sy[j], z = ut.st.sz[j];
            float sj = x * x + y * y + z * z;
            float d2 = fmaxf(sc + sj - 2.0f * (cx * x + cy * y + cz * z), 0.0f);
            bool prd = d2 < r2;
            unsigned long long mask = __ballot(prd);
            if (prd) {
                int pos = cnt + (int)__popcll(mask & ((1ull << lane) - 1ull));
                if (pos < ns) gidxL[c * ns + pos] = (unsigned short)j;
            }
            cnt += (int)__popcll(mask);
        }
        if (lane == 0) scnt[c] = min(cnt, ns);  // cnt>=1 (center is in the cloud)
    }
    __syncthreads();
    // ---- packed exclusive prefix scan over 102 entries: wave 0 only ----
    if (wid == 0) {
        // lane l owns entries 2l, 2l+1 (zero-padded past 101)
        int e0 = (2 * lane < NPOINT) ? scnt[2 * lane] : 0;
        int e1 = (2 * lane + 1 < NPOINT) ? scnt[2 * lane + 1] : 0;
        int p0 = e0 | ((e0 + (e0 < ns ? 1 : 0)) << 16);
        int p1 = e1 | ((e1 + (e1 < ns ? 1 : 0)) << 16);
        int local = p0 + p1;
        int incl = local;
        for (int d = 1; d < 64; d <<= 1) {
            int t = __shfl_up(incl, d, 64);
            if (lane >= d) incl += t;
        }
        int excl = incl - local;
        if (2 * lane <= NPOINT) spre[2 * lane] = excl;
        if (2 * lane + 1 <= NPOINT) spre[2 * lane + 1] = excl + p0;
    }
    __syncthreads();
    int Q = spre[NPOINT] & 0xffff;
    int CC = spre[NPOINT] >> 16;
    int CCpad = (CC + 31) & ~31;                  // <= 2464
    // ---- stage compressed candidates (reads ut.st -> writes cX/cY/cZ) ----
    float* fX = (float*)cX; float* fY = (float*)cY; float* fZ = (float*)cZ;
    for (int s = tid; s < CCpad; s += 1024) {
        float x = 1e30f, y = 1e30f, z = 1e30f;
        if (s < CC) {
            int lo = 0, hi = NPOINT - 1;
#pragma unroll
            for (int it = 0; it < 7; ++it) {
                int mid = (lo + hi + 1) >> 1;
                bool ge = ((spre[mid] >> 16) <= s);
                lo = ge ? mid : lo;
                hi = ge ? hi : mid - 1;
            }
            int p = s - (spre[lo] >> 16);
            int dup = (scnt[lo] < ns) ? 1 : 0;
            int id = gidxL[lo * ns + max(0, p - dup)];
            x = ut.st.sx[id]; y = ut.st.sy[id]; z = ut.st.sz[id];
        }
        fX[s] = x; fY[s] = y; fZ[s] = z;
    }
    __syncthreads();  // ut.st dead from here; ut.pm live (union)
    // ---- weighted compacted queries: tiles of 128, waves split candidates ----
    int CHp = CCpad >> 5;                          // v2f pairs per wave
    int j0p = wid * CHp;
    double racc = 0.0;
    for (int tb = 0; tb < Q; tb += 128) {
        float qx[2], qy[2], qz[2];
        double wgt[2];
#pragma unroll
        for (int hh = 0; hh < 2; hh++) {
            int q = tb + lane + 64 * hh;
            qx[hh] = 0.f; qy[hh] = 0.f; qz[hh] = 0.f; wgt[hh] = 0.0;
            if (q < Q) {
                int lo = 0, hi = NPOINT - 1;
#pragma unroll
                for (int it = 0; it < 7; ++it) {
                    int mid = (lo + hi + 1) >> 1;
                    bool ge = ((spre[mid] & 0xffff) <= q);
                    lo = ge ? mid : lo;
                    hi = ge ? hi : mid - 1;
                }
                int p = q - (spre[lo] & 0xffff);
                int dup = (scnt[lo] < ns) ? 1 : 0;
                int cslot = (spre[lo] >> 16) + (p == 0 ? 0 : p + dup);
                qx[hh] = fX[cslot]; qy[hh] = fY[cslot]; qz[hh] = fZ[cslot];
                wgt[hh] = (p == 0) ? (double)(1 + ns - scnt[lo]) : 1.0;
            }
        }
        v2f qax = {qx[0], qx[0]}, qay = {qy[0], qy[0]}, qaz = {qz[0], qz[0]};
        v2f qbx = {qx[1], qx[1]}, qby = {qy[1], qy[1]}, qbz = {qz[1], qz[1]};
        v2f m1A = {1e30f, 1e30f}, m2A = {1e30f, 1e30f};
        v2f m1B = {1e30f, 1e30f}, m2B = {1e30f, 1e30f};
#pragma unroll 4
        for (int jj = 0; jj < CHp; jj++) {
            v2f X = cX[j0p + jj], Y = cY[j0p + jj], Z = cZ[j0p + jj];
            // direct formula: exact 0 for bit-identical duplicates
            v2f dxA = qax - X, dyA = qay - Y, dzA = qaz - Z;
            v2f dA = dxA * dxA + dyA * dyA + dzA * dzA;
            float l0 = fminf(m1A.x, dA.x), h0 = fmaxf(m1A.x, dA.x);
            float l1 = fminf(m1A.y, dA.y), h1 = fmaxf(m1A.y, dA.y);
            m1A = (v2f){l0, l1};
            m2A = (v2f){fminf(m2A.x, h0), fminf(m2A.y, h1)};
            v2f dxB = qbx - X, dyB = qby - Y, dzB = qbz - Z;
            v2f dB = dxB * dxB + dyB * dyB + dzB * dzB;
            float l2 = fminf(m1B.x, dB.x), h2 = fmaxf(m1B.x, dB.x);
            float l3 = fminf(m1B.y, dB.y), h3 = fmaxf(m1B.y, dB.y);
            m1B = (v2f){l2, l3};
            m2B = (v2f){fminf(m2B.x, h2), fminf(m2B.y, h3)};
        }
        // merge even/odd streams (multiset (min1,min2) is order-independent -> exact)
        float a1 = fminf(m1A.x, m1A.y);
        float a2 = fminf(fmaxf(m1A.x, m1A.y), fminf(m2A.x, m2A.y));
        float b1 = fminf(m1B.x, m1B.y);
        float b2 = fminf(fmaxf(m1B.x, m1B.y), fminf(m2B.x, m2B.y));
        ut.pm.pm1[wid][lane] = a1; ut.pm.pm2[wid][lane] = a2;
        ut.pm.pm1[wid][64 + lane] = b1; ut.pm.pm2[wid][64 + lane] = b2;
        __syncthreads();
        if (tid < 128) {
            float c1 = ut.pm.pm1[0][tid], c2 = ut.pm.pm2[0][tid];
#pragma unroll
            for (int w = 1; w < 16; w++) {
                float d1 = ut.pm.pm1[w][tid], d2 = ut.pm.pm2[w][tid];
                float n1 = fminf(c1, d1);
                float n2 = fminf(fmaxf(c1, d1), fminf(c2, d2));
                c1 = n1; c2 = n2;
            }
            int q = tb + tid;
            double v = 0.0;
            if (q < Q) v = wgt[tid >> 6] * (double)(sqrtf(c2) + 1e-8f);
            for (int off = 32; off; off >>= 1) v += __shfl_down(v, off, 64);
            if ((tid & 63) == 0) racc += v;
        }
        __syncthreads();  // pm reuse next tile
    }
    if (tid == 0) part[OFF_UK + grp * 2 + 0] = racc;
    if (tid == 64) part[OFF_UK + grp * 2 + 1] = racc;
    // -------- last-block-done: fused finalize --------
    __threadfence();
    __syncthreads();
    if (tid == 0) lastFlag = (atomicAdd(done, 1) == 39);
    __syncthreads();
    if (!lastFlag) return;
    __threadfence();
    if (tid >= 64) return;
    double s0 = 0.0, s1 = 0.0, sr = 0.0;
#pragma unroll
    for (int k = 0; k < 4; k++) {
        s0 += aload_d(&part[OFF_CD + lane + 64 * k]);
        s1 += aload_d(&part[OFF_CD + 256 + lane + 64 * k]);
        sr += aload_d(&part[OFF_REP + lane + 64 * k]);
    }
    double v = 0.0;
    if (lane < 40) {
        int pi2 = lane >> 3;
        double m = aload_d(&part[OFF_UK + lane * 2]) + aload_d(&part[OFF_UK + lane * 2 + 1]);
        double p = c_p[pi2];
        int M2 = NPOINT * c_ns[pi2];
        double disk_area = M_PI * 1.0 / (double)NN;
        double e = sqrt(disk_area);
        m = m / (double)M2;
        double d = m - e;
        double w = (p * 100.0) * (p * 100.0);
        v = d * d / (e + 1e-8) * w / 40.0;  // /(8 batches * 5 percentages)
    }
    for (int off = 32; off; off >>= 1) {
        v += __shfl_down(v, off, 64);
        s0 += __shfl_down(s0, off, 64);
        s1 += __shfl_down(s1, off, 64);
        sr += __shfl_down(sr, off, 64);
    }
    if (lane == 0) {
        double cd = (0.8 * s0 + 0.2 * s1) / ((double)BB * NN) / (double)radius[0];
        double rep = sr / ((double)BB * NN * 4.0);
        out[0] = (float)(cd + rep + v);
    }
}

extern "C" void kernel_launch(void* const* d_in, const int* in_sizes, int n_in,
                              void* d_out, int out_size, void* d_ws, size_t ws_size,
                              hipStream_t stream) {
    const float* pred = (const float*)d_in[0];
    const float* gt = (const float*)d_in[1];
    const float* radius = (const float*)d_in[2];
    float* out = (float*)d_out;

    double* part = (double*)d_ws;            // 896 doubles of per-block partials
    int* ints = (int*)(part + N_DBL);
    int* done = ints;                        // zeroed by phase1 block 8
    int* fidx = ints + 16;                   // 8*102

    hipLaunchKernelGGL(k_phase1, dim3(520), dim3(256), 0, stream, pred, gt, fidx, part, done);
    hipLaunchKernelGGL(k_tail, dim3(40), dim3(1024), 0, stream, pred, fidx, part, done,
                       radius, out);
}